// Round 10
// baseline (10784.401 us; speedup 1.0000x reference)
//
#include <hip/hip_runtime.h>
#include <stdint.h>
#include <stddef.h>

typedef _Float16 f16;
typedef _Float16 f16x8 __attribute__((ext_vector_type(8)));
typedef float f32x4 __attribute__((ext_vector_type(4)));
typedef int i32x4 __attribute__((ext_vector_type(4)));

#define MFMA16(a, b, c) __builtin_amdgcn_mfma_f32_16x16x32_f16((a), (b), (c), 0, 0, 0)

static constexpr int kB = 64;
static constexpr int kT = 256;
static constexpr int kD = 1024;
static constexpr int kH = 1024;
static constexpr int kG = 4096;
static constexpr int kSlot = 64 * 1024;        // f16 per h slot [128 owner][64 row][8]
static constexpr int kNSlots = kT + 1;
static constexpr size_t kHistE = (size_t)kNSlots * kSlot;

__device__ __forceinline__ float fast_sigmoid(float x) {
  return __builtin_amdgcn_rcpf(1.f + __expf(-x));
}
__device__ __forceinline__ float fast_tanh(float x) {
  x = fminf(9.f, fmaxf(-9.f, x));
  const float e = __expf(2.f * x);
  return (e - 1.f) * __builtin_amdgcn_rcpf(e + 1.f);
}

// ---- x [64][256][1024] f32 -> xp[t][owner=d>>3][b][d&7] f16 ----
__global__ void x_perm_cvt(const float* __restrict__ x, f16* __restrict__ xp) {
  const size_t id = (size_t)blockIdx.x * 256 + threadIdx.x;
  const int d8 = (int)(id & 127) << 3;
  const int b = (int)(id >> 7) & 63;
  const int t = (int)(id >> 13);
  const float* s = x + (((size_t)b * kT + t) << 10) + d8;
  float4 a = *(const float4*)(s);
  float4 c = *(const float4*)(s + 4);
  f16x8 o;
  o[0] = (f16)a.x; o[1] = (f16)a.y; o[2] = (f16)a.z; o[3] = (f16)a.w;
  o[4] = (f16)c.x; o[5] = (f16)c.y; o[6] = (f16)c.z; o[7] = (f16)c.w;
  *(f16x8*)(xp + (size_t)t * kSlot + (size_t)(d8 >> 3) * 512 + b * 8) = o;
}

// ---- transpose+convert 4 layers: [1024][4096] f32 -> [4096][1024] f16 ----
__global__ void transpose_cvt_z(const float* __restrict__ src, f16* __restrict__ dst) {
  __shared__ float tile[32][33];
  const int z = blockIdx.z;
  const int c0 = blockIdx.x * 32;
  const int r0 = blockIdx.y * 32;
  const float* s = src + (size_t)z * kD * kG;
  f16* d = dst + (size_t)z * kG * kD;
  for (int rr = threadIdx.y; rr < 32; rr += 8)
    tile[rr][threadIdx.x] = s[(size_t)(r0 + rr) * kG + c0 + threadIdx.x];
  __syncthreads();
  for (int cc = threadIdx.y; cc < 32; cc += 8)
    d[(size_t)(c0 + cc) * kD + r0 + threadIdx.x] = (f16)tile[threadIdx.x][cc];
}

// ======================= 4-layer single-dispatch scan =======================
// 256 WGs x 1024 thr (1/CU). pairsel=(bid>>3)&1 -> layers (0,1) or (2,3);
// wgl = (bid>>4)*8 + (bid&7) in 0..127 owns units [wgl*8,+8) of both layers.
// LDS: U_even + U_odd (128 KB) + 4-slot below-term ring (16 KB) + hstage.
// Waves: w0-3  even-layer recurrence (U_e MFMA + ring-read + finalize+publish)
//        w4-7  odd-layer recurrence (U_o + W_odd-stream MFMA + finalize+publish)
//        w8    poller even flags -> ready[0];  w9 poller odd flags -> ready[1]
//        w10-13 ring producers: below-term (x@W0 or h1@W2, nt W loads), 2 steps/chunk
//        w14   (pair B only) poller layer-1 flags -> ready[2];  w15 exits
#define POLL512(basep, tgt)                                                    \
  {                                                                            \
    const int* pp = (basep) + l * 8;                                           \
    for (;;) {                                                                 \
      i32x4 pa, pb;                                                            \
      asm volatile("global_load_dwordx4 %0, %2, off sc0 sc1\n\t"               \
                   "global_load_dwordx4 %1, %3, off sc0 sc1\n\t"               \
                   "s_waitcnt vmcnt(0)"                                        \
                   : "=v"(pa), "=v"(pb) : "v"(pp), "v"(pp + 4) : "memory");    \
      const bool ok = pa[0] >= (tgt) && pa[1] >= (tgt) && pa[2] >= (tgt) &&    \
                      pa[3] >= (tgt) && pb[0] >= (tgt) && pb[1] >= (tgt) &&    \
                      pb[2] >= (tgt) && pb[3] >= (tgt);                        \
      if (__all(ok)) break;                                                    \
      __builtin_amdgcn_s_sleep(1);                                             \
    }                                                                          \
  }

#define GATES_BLOCK(Z0, Z1, CREG, HV)                                          \
  {                                                                            \
    const float q0 = __shfl_xor((Z0), 8);                                      \
    const float q1 = __shfl_xor((Z1), 8);                                      \
    const float zi = (lr & 8) ? q0 : (Z0);                                     \
    const float zf = (lr & 8) ? (Z0) : q0;                                     \
    const float zg = (lr & 8) ? q1 : (Z1);                                     \
    const float zo = (lr & 8) ? (Z1) : q1;                                     \
    const float iv = fast_sigmoid(zi);                                         \
    const float fv = fast_sigmoid(zf);                                         \
    const float gv = fast_tanh(zg);                                            \
    const float ov = fast_sigmoid(zo);                                         \
    const float cn = fv * (CREG) + iv * gv;                                    \
    (CREG) = cn;                                                               \
    (HV) = ov * fast_tanh(cn);                                                 \
  }

__launch_bounds__(1024, 1)
__global__ void lstm_scan4(const f16* __restrict__ xp,
                           const f16* __restrict__ Wt4,
                           const f16* __restrict__ Ut4,
                           f16* __restrict__ hist4,
                           int* __restrict__ flags4,
                           const float* __restrict__ bs4,
                           float* __restrict__ out32) {
  __shared__ f16 Ue[2][32][64][8];     // 64 KB
  __shared__ f16 Uo[2][32][64][8];     // 64 KB
  __shared__ f16 ring[4][64][32];      // 16 KB below-term (bias folded)
  __shared__ f16 hstage[8][16][8];     // 2 KB
  __shared__ int ready[3];
  __shared__ int prodR[4];
  __shared__ int consR[4];

  const int bid = blockIdx.x;
  const int pairsel = (bid >> 3) & 1;
  const int wgl = (bid >> 4) * 8 + (bid & 7);
  const int hbase = wgl * 8;
  const int leven = pairsel * 2, lodd = leven + 1;
  const int tid = threadIdx.x;
  const int l = tid & 63, w = tid >> 6;
  const int lr = l & 15, lq = l >> 4;

  const f16* Ute = Ut4 + (size_t)leven * kG * kD;
  const f16* Uto = Ut4 + (size_t)lodd * kG * kD;
  const f16* We = Wt4 + (size_t)leven * kG * kD;   // ring producers (nt)
  const f16* Wo = Wt4 + (size_t)lodd * kG * kD;    // odd waves (cached)
  f16* he_hist = hist4 + (size_t)leven * kHistE;
  f16* ho_hist = hist4 + (size_t)lodd * kHistE;
  int* flags_e = flags4 + leven * 512;
  int* flags_o = flags4 + lodd * 512;
  const int* flags_l1 = flags4 + 1 * 512;
  const float* bias_e = bs4 + leven * kG;
  const float* bias_o = bs4 + lodd * kG;
  // ring source: layer0 -> xp slot t; layer2 -> h1 slot t+1
  const f16* ringsrc = pairsel ? (hist4 + kHistE) : xp;

  if (tid == 0) {
    ready[0] = -1; ready[1] = -1; ready[2] = -1;
  }
  if (tid < 4) { prodR[tid] = -1; consR[tid] = -1; }

  // ---- stage U_even and U_odd into LDS (all 16 waves) ----
#pragma unroll
  for (int ff = 0; ff < 16; ++ff) {
    const int f = tid * 16 + ff;
    const int idx = f & 8191;
    const int xq = (idx >> 11) & 1, kkg = (idx >> 6) & 31, fl = idx & 63;
    const int flr = fl & 15, flq = fl >> 4;
    const int r = xq * 16 + flr;
    const int grow = (r >> 3) * 1024 + hbase + (r & 7);
    const f16* src = (f < 8192) ? Ute : Uto;
    f16* dst = (f < 8192) ? &Ue[xq][kkg][fl][0] : &Uo[xq][kkg][fl][0];
    *(f16x8*)dst = *(const f16x8*)(src + (size_t)grow * 1024 + kkg * 32 + flq * 8);
  }
  __syncthreads();   // the only workgroup barrier (before divergent role loops)

  const int row8 = 0;  (void)row8;

  // =================== roles ===================
  if (w < 4) {
    // ---- even-layer recurrence wave (bw = w) ----
    const int bw = w;
    const int rowoff = (bw * 16 + lr) * 8;
    const int brow = bw * 16 + lq * 4;
    const int ugl = hbase + (lr & 7);  (void)ugl;
    int* fpub = flags_e + (wgl * 4 + bw);
    float c_reg[4] = {0.f, 0.f, 0.f, 0.f};
    volatile int* rdy0 = &ready[0];
    volatile int* prp = &prodR[bw];

    for (int t = 0; t < 256; ++t) {
      while (*rdy0 < t) {}
      __asm__ __volatile__("" ::: "memory");
      const f16* hp = he_hist + (size_t)t * kSlot + lq * 512 + rowoff;
      f32x4 a0 = {}, a1 = {};
#pragma unroll 1
      for (int base = 0; base < 32; base += 4) {
        f16x8 ha[4];
#pragma unroll
        for (int j = 0; j < 4; ++j) ha[j] = *(const f16x8*)(hp + (size_t)(base + j) * 2048);
#pragma unroll
        for (int j = 0; j < 4; ++j) {
          a0 = MFMA16(ha[j], *(const f16x8*)&Ue[0][base + j][l][0], a0);
          a1 = MFMA16(ha[j], *(const f16x8*)&Ue[1][base + j][l][0], a1);
        }
      }
      while (*prp < t) {}
      __asm__ __volatile__("" ::: "memory");
      float hv[4];
#pragma unroll
      for (int j = 0; j < 4; ++j) {
        const float z0 = a0[j] + (float)ring[t & 3][brow + j][lr];
        const float z1 = a1[j] + (float)ring[t & 3][brow + j][16 + lr];
        GATES_BLOCK(z0, z1, c_reg[j], hv[j]);
      }
      __asm__ __volatile__("" ::: "memory");
      *(volatile int*)&consR[bw] = t;

      if (lr < 8) {
#pragma unroll
        for (int j = 0; j < 4; ++j) hstage[w][lq * 4 + j][lr] = (f16)hv[j];
      }
      if (l < 16) {
        const f16x8 hrow = *(const f16x8*)&hstage[w][l][0];
        f16* dst = he_hist + (size_t)(t + 1) * kSlot + ((size_t)wgl * 64 + bw * 16 + l) * 8;
        asm volatile("global_store_dwordx4 %0, %1, off sc0 sc1"
                     :: "v"(dst), "v"(hrow) : "memory");
      }
      asm volatile("s_waitcnt vmcnt(0)" ::: "memory");
      if (l == 0) {
        const int val = t + 1;
        asm volatile("global_store_dword %0, %1, off sc0 sc1"
                     :: "v"(fpub), "v"(val) : "memory");
      }
    }
  } else if (w < 8) {
    // ---- odd-layer recurrence wave (bw = w-4): U_o + streamed W_o ----
    const int bw = w - 4;
    const int rowoff = (bw * 16 + lr) * 8;
    const int brow = bw * 16 + lq * 4;
    const int ugl = hbase + (lr & 7);
    int* fpub = flags_o + (wgl * 4 + bw);
    const float bvo0 = bias_o[((lr < 8) ? 0 : 1024) + hbase + (lr & 7)];
    const float bvo1 = bias_o[((lr < 8) ? 2048 : 3072) + hbase + (lr & 7)];
    const int grow0 = (lr >> 3) * 1024 + hbase + (lr & 7);
    const int grow1 = (2 + (lr >> 3)) * 1024 + hbase + (lr & 7);
    const f16* wo0 = Wo + (size_t)grow0 * 1024 + lq * 8;
    const f16* wo1 = Wo + (size_t)grow1 * 1024 + lq * 8;
    float c_reg[4] = {0.f, 0.f, 0.f, 0.f};
    volatile int* rdy0 = &ready[0];
    volatile int* rdy1 = &ready[1];

    for (int to = 0; to < 256; ++to) {
      while (*rdy1 < to) {}
      while (*rdy0 < to + 1) {}
      __asm__ __volatile__("" ::: "memory");
      const f16* hpo = ho_hist + (size_t)to * kSlot + lq * 512 + rowoff;
      const f16* hpe = he_hist + (size_t)(to + 1) * kSlot + lq * 512 + rowoff;
      f32x4 u0 = {}, u1 = {}, x0 = {}, x1 = {};
#pragma unroll 1
      for (int base = 0; base < 32; base += 4) {
        f16x8 hao[4], hae[4], b0[4], b1[4];
#pragma unroll
        for (int j = 0; j < 4; ++j) {
          hao[j] = *(const f16x8*)(hpo + (size_t)(base + j) * 2048);
          hae[j] = *(const f16x8*)(hpe + (size_t)(base + j) * 2048);
          b0[j] = *(const f16x8*)(wo0 + (base + j) * 32);
          b1[j] = *(const f16x8*)(wo1 + (base + j) * 32);
        }
#pragma unroll
        for (int j = 0; j < 4; ++j) {
          u0 = MFMA16(hao[j], *(const f16x8*)&Uo[0][base + j][l][0], u0);
          u1 = MFMA16(hao[j], *(const f16x8*)&Uo[1][base + j][l][0], u1);
          x0 = MFMA16(hae[j], b0[j], x0);
          x1 = MFMA16(hae[j], b1[j], x1);
        }
      }
      float hv[4];
#pragma unroll
      for (int j = 0; j < 4; ++j) {
        const float z0 = u0[j] + x0[j] + bvo0;
        const float z1 = u1[j] + x1[j] + bvo1;
        GATES_BLOCK(z0, z1, c_reg[j], hv[j]);
      }
      if (lr < 8) {
#pragma unroll
        for (int j = 0; j < 4; ++j) hstage[w][lq * 4 + j][lr] = (f16)hv[j];
      }
      if (l < 16) {
        const f16x8 hrow = *(const f16x8*)&hstage[w][l][0];
        f16* dst = ho_hist + (size_t)(to + 1) * kSlot + ((size_t)wgl * 64 + bw * 16 + l) * 8;
        asm volatile("global_store_dwordx4 %0, %1, off sc0 sc1"
                     :: "v"(dst), "v"(hrow) : "memory");
      }
      asm volatile("s_waitcnt vmcnt(0)" ::: "memory");
      if (l == 0) {
        const int val = to + 1;
        asm volatile("global_store_dword %0, %1, off sc0 sc1"
                     :: "v"(fpub), "v"(val) : "memory");
      }
      if (pairsel && lr < 8) {  // layer 3: final output (off critical path)
#pragma unroll
        for (int j = 0; j < 4; ++j)
          out32[((size_t)(brow + j) * kT + to) * kH + ugl] = hv[j];
      }
    }
  } else if (w == 8) {
    for (int s = 0; s <= 256; ++s) {
      POLL512(flags_e, s);
      __asm__ __volatile__("" ::: "memory");
      *(volatile int*)&ready[0] = s;
    }
  } else if (w == 9) {
    for (int s = 0; s <= 255; ++s) {
      POLL512(flags_o, s);
      __asm__ __volatile__("" ::: "memory");
      *(volatile int*)&ready[1] = s;
    }
  } else if (w < 14) {
    // ---- ring producer wave (bw = w-10): below-term, 2 steps per chunk ----
    const int bw = w - 10;
    const int rowoff = (bw * 16 + lr) * 8;
    const int brow = bw * 16 + lq * 4;
    const float bve0 = bias_e[((lr < 8) ? 0 : 1024) + hbase + (lr & 7)];
    const float bve1 = bias_e[((lr < 8) ? 2048 : 3072) + hbase + (lr & 7)];
    const int grow0 = (lr >> 3) * 1024 + hbase + (lr & 7);
    const int grow1 = (2 + (lr >> 3)) * 1024 + hbase + (lr & 7);
    const f16* we0 = We + (size_t)grow0 * 1024 + lq * 8;
    const f16* we1 = We + (size_t)grow1 * 1024 + lq * 8;
    volatile int* rdy2 = &ready[2];
    volatile int* crp = &consR[bw];

    for (int c = 0; c < 128; ++c) {
      const int t0 = 2 * c, t1 = 2 * c + 1;
      if (pairsel) { while (*rdy2 < t1 + 1) {} }
      while (*crp < t0 - 3) {}
      __asm__ __volatile__("" ::: "memory");
      const f16* s0p = ringsrc + (size_t)(t0 + pairsel) * kSlot + lq * 512 + rowoff;
      const f16* s1p = ringsrc + (size_t)(t1 + pairsel) * kSlot + lq * 512 + rowoff;
      f32x4 p00 = {}, p01 = {}, p10 = {}, p11 = {};
#pragma unroll 1
      for (int base = 0; base < 32; base += 4) {
        f16x8 b0[4], b1[4], A0[4], A1[4];
#pragma unroll
        for (int j = 0; j < 4; ++j) {
          b0[j] = __builtin_nontemporal_load((const f16x8*)(we0 + (base + j) * 32));
          b1[j] = __builtin_nontemporal_load((const f16x8*)(we1 + (base + j) * 32));
          A0[j] = *(const f16x8*)(s0p + (size_t)(base + j) * 2048);
          A1[j] = *(const f16x8*)(s1p + (size_t)(base + j) * 2048);
        }
#pragma unroll
        for (int j = 0; j < 4; ++j) {
          p00 = MFMA16(A0[j], b0[j], p00);
          p01 = MFMA16(A0[j], b1[j], p01);
          p10 = MFMA16(A1[j], b0[j], p10);
          p11 = MFMA16(A1[j], b1[j], p11);
        }
      }
#pragma unroll
      for (int j = 0; j < 4; ++j) {
        ring[t0 & 3][brow + j][lr] = (f16)(p00[j] + bve0);
        ring[t0 & 3][brow + j][16 + lr] = (f16)(p01[j] + bve1);
        ring[t1 & 3][brow + j][lr] = (f16)(p10[j] + bve0);
        ring[t1 & 3][brow + j][16 + lr] = (f16)(p11[j] + bve1);
      }
      asm volatile("s_waitcnt lgkmcnt(0)" ::: "memory");
      *(volatile int*)&prodR[bw] = t1;
    }
  } else if (w == 14) {
    if (pairsel) {
      for (int s = 2; s <= 256; ++s) {
        POLL512((int*)flags_l1, s);
        __asm__ __volatile__("" ::: "memory");
        *(volatile int*)&ready[2] = s;
      }
    }
  }
  // w == 15 (and pairA w14): exit
}

// ---------------- host launch ----------------
extern "C" void kernel_launch(void* const* d_in, const int* in_sizes, int n_in,
                              void* d_out, int out_size, void* d_ws, size_t ws_size,
                              hipStream_t stream) {
  (void)in_sizes; (void)n_in; (void)out_size; (void)ws_size;
  const float* x = (const float*)d_in[0];
  const float* Ws = (const float*)d_in[1];
  const float* Us = (const float*)d_in[2];
  const float* bs = (const float*)d_in[3];
  char* ws = (char*)d_ws;

  const size_t kLayerW = (size_t)kG * kD * 2;              // 8 MB
  const size_t kHistB = kHistE * 2;                        // 33,685,504 B
  const size_t WT_OFF = 0;                                 // 32 MB
  const size_t UT_OFF = WT_OFF + 4 * kLayerW;              // 32 MB
  const size_t XP_OFF = UT_OFF + 4 * kLayerW;              // 33.5 MB
  const size_t HH_OFF = XP_OFF + (size_t)kT * kSlot * 2;   // 134.7 MB
  const size_t FL_OFF = HH_OFF + 4 * kHistB;               // 8 KB (total ~232.4 MB)

  f16* Wt = (f16*)(ws + WT_OFF);
  f16* Ut = (f16*)(ws + UT_OFF);
  f16* xp = (f16*)(ws + XP_OFF);
  f16* hh = (f16*)(ws + HH_OFF);
  int* fl = (int*)(ws + FL_OFF);

  x_perm_cvt<<<8192, 256, 0, stream>>>(x, xp);
  transpose_cvt_z<<<dim3(kG / 32, kD / 32, 4), dim3(32, 8), 0, stream>>>(Ws, Wt);
  transpose_cvt_z<<<dim3(kG / 32, kD / 32, 4), dim3(32, 8), 0, stream>>>(Us, Ut);
  for (int i = 0; i < 4; ++i)
    hipMemsetAsync(ws + HH_OFF + i * kHistB, 0, (size_t)kSlot * 2, stream);
  hipMemsetAsync(ws + FL_OFF, 0, 4 * 512 * 4, stream);

  lstm_scan4<<<256, 1024, 0, stream>>>(xp, Wt, Ut, hh, fl, bs, (float*)d_out);
}

// Round 11
// 3701.280 us; speedup vs baseline: 2.9137x; 2.9137x over previous
//
#include <hip/hip_runtime.h>
#include <stdint.h>
#include <stddef.h>

typedef _Float16 f16;
typedef _Float16 f16x8 __attribute__((ext_vector_type(8)));
typedef float f32x4 __attribute__((ext_vector_type(4)));
typedef int i32x4 __attribute__((ext_vector_type(4)));

#define MFMA16(a, b, c) __builtin_amdgcn_mfma_f32_16x16x32_f16((a), (b), (c), 0, 0, 0)

static constexpr int kB = 64;
static constexpr int kT = 256;
static constexpr int kD = 1024;
static constexpr int kH = 1024;
static constexpr int kG = 4096;
static constexpr int kSlot = 64 * 1024;          // f16 per h slot [128 owner][64 row][8]
static constexpr int kNSlots = kT + 1;
static constexpr size_t kHistE = (size_t)kNSlots * kSlot;

__device__ __forceinline__ float fast_sigmoid(float x) {
  return __builtin_amdgcn_rcpf(1.f + __expf(-x));
}
__device__ __forceinline__ float fast_tanh(float x) {
  x = fminf(9.f, fmaxf(-9.f, x));
  const float e = __expf(2.f * x);
  return (e - 1.f) * __builtin_amdgcn_rcpf(e + 1.f);
}

// ---- x [64][256][1024] f32 -> xp[t][owner=d>>3][b][d&7] f16 ----
__global__ void x_perm_cvt(const float* __restrict__ x, f16* __restrict__ xp) {
  const size_t id = (size_t)blockIdx.x * 256 + threadIdx.x;
  const int d8 = (int)(id & 127) << 3;
  const int b = (int)(id >> 7) & 63;
  const int t = (int)(id >> 13);
  const float* s = x + (((size_t)b * kT + t) << 10) + d8;
  float4 a = *(const float4*)(s);
  float4 c = *(const float4*)(s + 4);
  f16x8 o;
  o[0] = (f16)a.x; o[1] = (f16)a.y; o[2] = (f16)a.z; o[3] = (f16)a.w;
  o[4] = (f16)c.x; o[5] = (f16)c.y; o[6] = (f16)c.z; o[7] = (f16)c.w;
  *(f16x8*)(xp + (size_t)t * kSlot + (size_t)(d8 >> 3) * 512 + b * 8) = o;
}

// ---- transpose+convert 4 layers: [1024][4096] f32 -> [4096][1024] f16 ----
__global__ void transpose_cvt_z(const float* __restrict__ src, f16* __restrict__ dst) {
  __shared__ float tile[32][33];
  const int z = blockIdx.z;
  const int c0 = blockIdx.x * 32;
  const int r0 = blockIdx.y * 32;
  const float* s = src + (size_t)z * kD * kG;
  f16* d = dst + (size_t)z * kG * kD;
  for (int rr = threadIdx.y; rr < 32; rr += 8)
    tile[rr][threadIdx.x] = s[(size_t)(r0 + rr) * kG + c0 + threadIdx.x];
  __syncthreads();
  for (int cc = threadIdx.y; cc < 32; cc += 8)
    d[(size_t)(c0 + cc) * kD + r0 + threadIdx.x] = (f16)tile[threadIdx.x][cc];
}

// ---------------- 2-layer pipelined LSTM scan (r8 + micro-opts) ----------------
// 256 WGs x 1024 thr. layerbit = bid&1, wgl = bid>>1 owns units [wgl*8,+8).
// Weights slice [W;U] (concat K=2048) in LDS (128 KB).
// h slot layout: [owner(128)][row(64)][unit(8)]; publish = 1 dwordx4 sc0sc1/lane.
// r11 deltas vs r8: f16 double-buffered reduction (1 sync/step), busy-poll
// pollers, all 16 h loads hoisted before the MFMA chain.
__launch_bounds__(1024, 1)
__global__ void lstm_scan2(const f16* __restrict__ below_lo,
                           const f16* __restrict__ Wt_lo, const f16* __restrict__ Ut_lo,
                           const f16* __restrict__ Wt_hi, const f16* __restrict__ Ut_hi,
                           f16* __restrict__ hist_lo, f16* __restrict__ hist_hi,
                           int* __restrict__ flags_lo, int* __restrict__ flags_hi,
                           const float* __restrict__ bias_lo,
                           const float* __restrict__ bias_hi,
                           float* __restrict__ out32) {
  __shared__ f16 Cw[8192 * 8];              // 128 KB
  __shared__ f16 red0h[2][12 * 64 * 4];     // 12 KB (f16 partials, dbuf)
  __shared__ f16 red1h[2][12 * 64 * 4];     // 12 KB
  __shared__ f16 hstage[4][16][8];          // 2 KB
  __shared__ int lds_ready[2];

  const int bid = blockIdx.x;
  const int layerbit = bid & 1;
  const int wgl = bid >> 1;
  const int hbase = wgl * 8;
  const int tid = threadIdx.x;
  const int l = tid & 63, w = tid >> 6;
  const int lr = l & 15, lq = l >> 4;
  const int bw = w & 3, kw = w >> 2;

  const f16* Wt = layerbit ? Wt_hi : Wt_lo;
  const f16* Ut = layerbit ? Ut_hi : Ut_lo;
  f16* own_hist = layerbit ? hist_hi : hist_lo;
  const f16* below_base = layerbit ? (hist_lo + kSlot) : below_lo; // upper: slot t+1
  const int* fpoll_own = layerbit ? flags_hi : flags_lo;
  const int* fpoll_below = flags_lo;
  int* fpub = (layerbit ? flags_hi : flags_lo) + (wgl * 4 + bw);
  const float* bias = layerbit ? bias_hi : bias_lo;

  if (tid == 0) {
    lds_ready[0] = layerbit ? -1 : (1 << 30);  // lower's below always ready
    lds_ready[1] = 0;                          // own slot 0 pre-zeroed
  }

  // ---- stage weights slice into LDS ----
#pragma unroll
  for (int ff = 0; ff < 8; ++ff) {
    const int f = tid * 8 + ff;
    const int x = f >> 12, kkg = (f >> 6) & 63, fl = f & 63;
    const int flr = fl & 15, flq = fl >> 4;
    const int r = x * 16 + flr;
    const int grow = (r >> 3) * 1024 + hbase + (r & 7);
    const f16* src = (kkg < 32) ? Wt : Ut;
    *(f16x8*)&Cw[f * 8] =
        *(const f16x8*)(src + (size_t)grow * 1024 + (kkg & 31) * 32 + flq * 8);
  }

  float bv0 = 0.f, bv1 = 0.f;
  if (kw == 0) {
    bv0 = bias[((lr < 8) ? 0 : 1024) + hbase + (lr & 7)];
    bv1 = bias[((lr < 8) ? 2048 : 3072) + hbase + (lr & 7)];
  }
  __syncthreads();

  const int brow = bw * 16 + lq * 4;
  const int ugl = hbase + (lr & 7);
  const int* pollp = ((w == 0) ? fpoll_below : fpoll_own) + l * 8;
  const int row = bw * 16 + lr;

  float c_reg[4] = {0.f, 0.f, 0.f, 0.f};

#pragma unroll 1
  for (int t = 0; t < kT; ++t) {
    // ---- readiness (busy-poll, no sleep) ----
    if (w == 0) {
      if (layerbit) {
        const int tgt = t + 1;
        for (;;) {
          i32x4 pa, pb;
          asm volatile("global_load_dwordx4 %0, %2, off sc0 sc1\n\t"
                       "global_load_dwordx4 %1, %3, off sc0 sc1\n\t"
                       "s_waitcnt vmcnt(0)"
                       : "=v"(pa), "=v"(pb) : "v"(pollp), "v"(pollp + 4) : "memory");
          const bool ok = pa[0] >= tgt && pa[1] >= tgt && pa[2] >= tgt && pa[3] >= tgt &&
                          pb[0] >= tgt && pb[1] >= tgt && pb[2] >= tgt && pb[3] >= tgt;
          if (__all(ok)) break;
        }
        __asm__ __volatile__("" ::: "memory");
        *(volatile int*)&lds_ready[0] = t;
      }
    } else if (w == 8) {
      const int tgt = t;
      for (;;) {
        i32x4 pa, pb;
        asm volatile("global_load_dwordx4 %0, %2, off sc0 sc1\n\t"
                     "global_load_dwordx4 %1, %3, off sc0 sc1\n\t"
                     "s_waitcnt vmcnt(0)"
                     : "=v"(pa), "=v"(pb) : "v"(pollp), "v"(pollp + 4) : "memory");
        const bool ok = pa[0] >= tgt && pa[1] >= tgt && pa[2] >= tgt && pa[3] >= tgt &&
                        pb[0] >= tgt && pb[1] >= tgt && pb[2] >= tgt && pb[3] >= tgt;
        if (__all(ok)) break;
      }
      __asm__ __volatile__("" ::: "memory");
      *(volatile int*)&lds_ready[1] = t;
    }
    {
      volatile int* rdy = &lds_ready[kw >> 1];
      while (*rdy < t) __builtin_amdgcn_s_sleep(1);
      __asm__ __volatile__("" ::: "memory");
    }

    // ---- all 16 h loads hoisted (plain cached; owner-block layout) ----
    const f16* hsrc = (kw < 2) ? (below_base + (size_t)t * kSlot)
                               : (own_hist + (size_t)t * kSlot);
    const f16* hp = hsrc + (size_t)((kw & 1) * 64 + lq) * 512 + row * 8;
    f16x8 ha[16];
#pragma unroll
    for (int ii = 0; ii < 16; ++ii)
      ha[ii] = *(const f16x8*)(hp + (size_t)ii * 2048);

    // ---- 32 MFMAs over this wave's 512-wide K chunk ----
    f32x4 acc0 = {}, acc1 = {};
    const int kkb = kw * 16;
#pragma unroll
    for (int ii = 0; ii < 16; ++ii) {
      const f16x8 b0 = *(const f16x8*)&Cw[((kkb + ii) * 64 + l) * 8];
      const f16x8 b1 = *(const f16x8*)&Cw[((4096 + (kkb + ii) * 64) + l) * 8];
      acc0 = MFMA16(ha[ii], b0, acc0);
      acc1 = MFMA16(ha[ii], b1, acc1);
    }

    // ---- kw1..3 partials -> LDS (f16, parity dbuf); single sync ----
    if (kw != 0) {
      const int rb = ((w - 4) * 64 + l) * 4;
#pragma unroll
      for (int j = 0; j < 4; ++j) {
        red0h[t & 1][rb + j] = (f16)acc0[j];
        red1h[t & 1][rb + j] = (f16)acc1[j];
      }
    }
    __syncthreads();

    if (kw == 0) {
      f32x4 s0 = acc0, s1 = acc1;
#pragma unroll
      for (int q = 0; q < 3; ++q) {
        const int rb = ((q * 4 + bw) * 64 + l) * 4;
#pragma unroll
        for (int j = 0; j < 4; ++j) {
          s0[j] += (float)red0h[t & 1][rb + j];
          s1[j] += (float)red1h[t & 1][rb + j];
        }
      }

      float hv[4];
#pragma unroll
      for (int j = 0; j < 4; ++j) {
        const float z0 = s0[j] + bv0;
        const float z1 = s1[j] + bv1;
        const float q0 = __shfl_xor(z0, 8);
        const float q1 = __shfl_xor(z1, 8);
        const float zi = (lr & 8) ? q0 : z0;
        const float zf = (lr & 8) ? z0 : q0;
        const float zg = (lr & 8) ? q1 : z1;
        const float zo = (lr & 8) ? z1 : q1;
        const float iv = fast_sigmoid(zi);
        const float fv = fast_sigmoid(zf);
        const float gv = fast_tanh(zg);
        const float ov = fast_sigmoid(zo);
        const float cn = fv * c_reg[j] + iv * gv;
        c_reg[j] = cn;
        hv[j] = ov * fast_tanh(cn);
      }

      // gather wave's 16 rows x 8 units, coalesced publish (1 dwordx4/lane)
      if (lr < 8) {
#pragma unroll
        for (int j = 0; j < 4; ++j)
          hstage[w][lq * 4 + j][lr] = (f16)hv[j];
      }
      if (l < 16) {
        const f16x8 hrow = *(const f16x8*)&hstage[w][l][0];
        f16* dst = own_hist + (size_t)(t + 1) * kSlot +
                   ((size_t)wgl * 64 + bw * 16 + l) * 8;
        asm volatile("global_store_dwordx4 %0, %1, off sc0 sc1"
                     :: "v"(dst), "v"(hrow) : "memory");
      }
      asm volatile("s_waitcnt vmcnt(0)" ::: "memory");
      if (l == 0) {
        const int val = t + 1;
        asm volatile("global_store_dword %0, %1, off sc0 sc1"
                     :: "v"(fpub), "v"(val) : "memory");
      }
      // final output (layer 3 only), off critical path
      if (out32 && layerbit && lr < 8) {
#pragma unroll
        for (int j = 0; j < 4; ++j)
          out32[((size_t)(brow + j) * kT + t) * kH + ugl] = hv[j];
      }
    }
  }
}

// ---------------- host launch ----------------
extern "C" void kernel_launch(void* const* d_in, const int* in_sizes, int n_in,
                              void* d_out, int out_size, void* d_ws, size_t ws_size,
                              hipStream_t stream) {
  (void)in_sizes; (void)n_in; (void)out_size; (void)ws_size;
  const float* x = (const float*)d_in[0];
  const float* Ws = (const float*)d_in[1];
  const float* Us = (const float*)d_in[2];
  const float* bs = (const float*)d_in[3];
  char* ws = (char*)d_ws;

  const size_t kLayerW = (size_t)kG * kD * 2;               // 8 MB
  const size_t kHistB = kHistE * 2;                         // 33,685,504 B
  const size_t WT_OFF = 0;                                  // 32 MB
  const size_t UT_OFF = WT_OFF + 4 * kLayerW;               // 32 MB
  const size_t XP_OFF = UT_OFF + 4 * kLayerW;               // 33.5 MB
  const size_t HH_OFF = XP_OFF + (size_t)kT * kSlot * 2;    // 134.7 MB
  const size_t FL_OFF = HH_OFF + 4 * kHistB;                // 8 KB

  f16* Wt = (f16*)(ws + WT_OFF);
  f16* Ut = (f16*)(ws + UT_OFF);
  f16* xp = (f16*)(ws + XP_OFF);
  int* fl = (int*)(ws + FL_OFF);

  f16* hist[4];
  for (int i = 0; i < 4; ++i) hist[i] = (f16*)(ws + HH_OFF + i * kHistB);

  x_perm_cvt<<<8192, 256, 0, stream>>>(x, xp);
  transpose_cvt_z<<<dim3(kG / 32, kD / 32, 4), dim3(32, 8), 0, stream>>>(Ws, Wt);
  transpose_cvt_z<<<dim3(kG / 32, kD / 32, 4), dim3(32, 8), 0, stream>>>(Us, Ut);
  for (int i = 0; i < 4; ++i)
    hipMemsetAsync(ws + HH_OFF + i * kHistB, 0, (size_t)kSlot * 2, stream);
  hipMemsetAsync(ws + FL_OFF, 0, 4 * 512 * 4, stream);

  // dispatch 1: layers 0 (lower) + 1 (upper)
  lstm_scan2<<<256, 1024, 0, stream>>>(
      xp, Wt, Ut, Wt + (size_t)kG * kD, Ut + (size_t)kG * kD,
      hist[0], hist[1], fl, fl + 512,
      bs, bs + kG, (float*)nullptr);
  // dispatch 2: layers 2 (lower, below = hist[1] slots t+1) + 3 (upper)
  lstm_scan2<<<256, 1024, 0, stream>>>(
      hist[1] + kSlot, Wt + 2 * (size_t)kG * kD, Ut + 2 * (size_t)kG * kD,
      Wt + 3 * (size_t)kG * kD, Ut + 3 * (size_t)kG * kD,
      hist[2], hist[3], fl + 1024, fl + 1536,
      bs + 2 * kG, bs + 3 * kG, (float*)d_out);
}